// Round 9
// baseline (687.622 us; speedup 1.0000x reference)
//
#include <hip/hip_runtime.h>
#include <hip/hip_bf16.h>

// Gaussian-kernel regression — single fused kernel with grid-wide barriers.
// Phase 1 (prep): 512 wave-tasks: 256x yt=y@R^T+t GEMM -> KA2C*yt perm + yn
//   hi/lo folded in K=144 slot; 256x V=X[1:] transpose perm. Per-wave LDS slice.
// Phase 2 (main): R5-proven: S via 9 MFMAs (exponent folded), exp2, P via
//   per-wave LDS round-trip, PV full-rate; js=12 j-splits, 3 blocks/CU.
// Phase 3 (fin): 512 block-tasks reduce splits + normalize + transpose + store.
// Grid 768 = 256 CU x 3 (LDS 52224 -> 3/CU) => co-resident; barrier = device
// atomic counter (monotonic, zeroed by hipMemsetAsync each launch).

#define LOG2E 1.44269504088896340736f
#define KNEG (-(1.0f/256.0f)*LOG2E)
#define KA2C (2.0f*(1.0f/256.0f)*LOG2E)

typedef __attribute__((ext_vector_type(4)))  float f32x4;
typedef __attribute__((ext_vector_type(16))) float f32x16;
typedef __attribute__((ext_vector_type(8)))  short bf16x8;

__device__ __forceinline__ unsigned short f2bf(float f) {
  unsigned u = __builtin_bit_cast(unsigned, f);
  u = (u + 0x7fffu + ((u >> 16) & 1u)) >> 16;  // RNE; inputs finite
  return (unsigned short)u;
}
__device__ __forceinline__ unsigned pk2bf(float a, float b) {
  __hip_bfloat162 h = __float22bfloat162_rn(float2{a, b});  // v_cvt_pk_bf16_f32
  unsigned u;
  __builtin_memcpy(&u, &h, 4);
  return u;
}
__device__ __forceinline__ bf16x8 pack8(float4 p0, float4 p1) {
  uint4 u;
  u.x = pk2bf(p0.x, p0.y); u.y = pk2bf(p0.z, p0.w);
  u.z = pk2bf(p1.x, p1.y); u.w = pk2bf(p1.z, p1.w);
  return __builtin_bit_cast(bf16x8, u);
}
__device__ __forceinline__ float fast_exp2(float x) {
#if __has_builtin(__builtin_amdgcn_exp2f)
  return __builtin_amdgcn_exp2f(x);
#else
  return exp2f(x);
#endif
}
__device__ __forceinline__ void gl2lds16(const void* g, void* l) {
  __builtin_amdgcn_global_load_lds((const __attribute__((address_space(1))) unsigned int*)g,
                                   (__attribute__((address_space(3))) unsigned int*)l, 16, 0, 0);
}
__device__ __forceinline__ f32x16 mfma_32x32x16(bf16x8 a, bf16x8 b, f32x16 c) {
  return __builtin_amdgcn_mfma_f32_32x32x16_bf16(a, b, c, 0, 0, 0);
}

#define T_STRIDE 34816   // per-64j-tile bytes: 2 jc x 9 kc x 1024 (yt) + 16384 (V)
#define V_OFF    18432
#define SMBYTES  52224   // stg 34816 + gls 17408 (R5 main-phase layout)

// Grid barrier: monotonic counter, all blocks co-resident by construction.
__device__ __forceinline__ void gridbar(unsigned* cnt, unsigned target) {
  __threadfence();          // release: flush this block's global stores
  __syncthreads();
  if (threadIdx.x == 0) {
    __hip_atomic_fetch_add(cnt, 1u, __ATOMIC_ACQ_REL, __HIP_MEMORY_SCOPE_AGENT);
    while (__hip_atomic_load(cnt, __ATOMIC_ACQUIRE, __HIP_MEMORY_SCOPE_AGENT) < target)
      __builtin_amdgcn_s_sleep(2);
  }
  __syncthreads();
  __threadfence();          // acquire: invalidate stale cache lines
}

__global__ __launch_bounds__(256, 3) void k_fused(
    const float* __restrict__ y,
    const float* __restrict__ R,
    const float* __restrict__ t,
    const float* __restrict__ X,
    unsigned short* __restrict__ ctp,
    unsigned* __restrict__ cnt,
    float* __restrict__ accp,
    float* __restrict__ rsp,
    float* __restrict__ out,
    int js) {
  __shared__ char smraw[SMBYTES];
  const int tid = threadIdx.x;
  const int wv = tid >> 6, ln = tid & 63;
  const int l = ln & 31, h = ln >> 5;
  const int nb = gridDim.x;

  // ================= Phase 1: prep (512 wave-tasks) =================
  {
    const int gw = blockIdx.x * 4 + wv;
    const int NW = nb * 4;
    char* slice = smraw + wv * 8704;    // per-wave LDS slice (4x8704=34816 <= SMBYTES)
    for (int task = gw; task < 512; task += NW) {
      __builtin_amdgcn_wave_barrier();
      if (task < 256) {
        // ---- yt task: 32 rows rw..rw+31; tile T=task>>1, jc half jcw=task&1 ----
        unsigned short* ytt = (unsigned short*)slice;        // [32][132]
        float* ynf = (float*)(slice + 8448);                 // 32 floats
        const int T = task >> 1, jcw = task & 1;
        const int rw = task * 32;
        bf16x8 af[8];
        {
          int row = rw + l; if (row > 8190) row = 8190;
          const float* yr = y + (size_t)row * 128;
#pragma unroll
          for (int kc = 0; kc < 8; ++kc) {
            float4 p0 = *(const float4*)(yr + kc*16 + 8*h);
            float4 p1 = *(const float4*)(yr + kc*16 + 8*h + 4);
            af[kc] = pack8(p0, p1);
          }
        }
        f32x16 ac[4];
#pragma unroll
        for (int cc=0; cc<4; ++cc)
#pragma unroll
          for (int i=0;i<16;++i) ac[cc][i] = 0.f;
#pragma unroll
        for (int cc=0; cc<4; ++cc) {
          const float* Rr = R + (size_t)(cc*32 + l) * 128;   // R^T[k][c] = R[c][k]
#pragma unroll
          for (int kc=0; kc<8; ++kc) {
            float4 p0 = *(const float4*)(Rr + kc*16 + 8*h);
            float4 p1 = *(const float4*)(Rr + kc*16 + 8*h + 4);
            ac[cc] = mfma_32x32x16(af[kc], pack8(p0, p1), ac[cc]);
          }
        }
        float tv0 = t[l], tv1 = t[32+l], tv2 = t[64+l], tv3 = t[96+l];
        float v0[16], v1[16], v2[16], v3[16], ssq[16];
#pragma unroll
        for (int r=0;r<16;++r) {
          v0[r]=ac[0][r]+tv0; v1[r]=ac[1][r]+tv1; v2[r]=ac[2][r]+tv2; v3[r]=ac[3][r]+tv3;
          ssq[r] = v0[r]*v0[r] + v1[r]*v1[r] + v2[r]*v2[r] + v3[r]*v3[r];
        }
#pragma unroll
        for (int off=1; off<32; off<<=1)
#pragma unroll
          for (int r=0;r<16;++r) ssq[r] += __shfl_xor(ssq[r], off, 64);
        if (l < 16) {
          int r = l;
          int grow = rw + (r&3) + 8*(r>>2) + 4*h;
          ynf[(r&3) + 8*(r>>2) + 4*h] = (grow >= 8191) ? -1.0e4f : KNEG * ssq[r];
        }
#pragma unroll
        for (int r=0;r<16;++r) {
          int rloc = (r&3) + 8*(r>>2) + 4*h;
          ytt[rloc*132 +   0 + l] = f2bf(KA2C * v0[r]);
          ytt[rloc*132 +  32 + l] = f2bf(KA2C * v1[r]);
          ytt[rloc*132 +  64 + l] = f2bf(KA2C * v2[r]);
          ytt[rloc*132 +  96 + l] = f2bf(KA2C * v3[r]);
        }
        __builtin_amdgcn_wave_barrier();
        char* base = (char*)ctp + (size_t)T*T_STRIDE;
#pragma unroll
        for (int kc=0;kc<8;++kc) {
          const unsigned short* s = &ytt[l*132 + kc*16 + 8*h];
          uint2 a = *(const uint2*)(s);
          uint2 b = *(const uint2*)(s + 4);
          uint4 o; o.x=a.x; o.y=a.y; o.z=b.x; o.w=b.y;
          *(uint4*)(base + (jcw*9 + kc)*1024 + ln*16) = o;
        }
        {  // kc=8 slot: k=128 -> yn_hi, k=129 -> yn_lo (h=0 lanes only)
          float yn = ynf[l];
          unsigned short hi = f2bf(yn);
          float hif = __builtin_bit_cast(float, (unsigned)hi << 16);
          unsigned short lo = f2bf(yn - hif);
          uint4 o; o.x = (h == 0) ? ((unsigned)hi | ((unsigned)lo << 16)) : 0u;
          o.y = 0u; o.z = 0u; o.w = 0u;
          *(uint4*)(base + (jcw*9 + 8)*1024 + ln*16) = o;
        }
      } else {
        // ---- V task: 32 X1-rows; tile T2=(task-256)>>1, half=(task-256)&1 ----
        unsigned short* xs = (unsigned short*)slice;         // [32][136] bf16
        const int tv_ = task - 256;
        const int T2 = tv_ >> 1, half = tv_ & 1;
        const int xr0 = T2*64 + half*32 + 1;
        {
          int rl = ln >> 1, ch2 = ln & 1;
          int row = xr0 + rl; if (row > 8191) row = 8191;   // pad j has g=0
          const float* src = X + (size_t)row*128 + ch2*64;
          unsigned short* dst = xs + rl*136 + ch2*64;
#pragma unroll
          for (int i=0;i<8;++i) {
            float4 p0 = *(const float4*)(src + i*8);
            float4 p1 = *(const float4*)(src + i*8 + 4);
            uint4 w;
            w.x = pk2bf(p0.x, p0.y); w.y = pk2bf(p0.z, p0.w);
            w.z = pk2bf(p1.x, p1.y); w.w = pk2bf(p1.z, p1.w);
            *(uint4*)(dst + i*8) = w;
          }
        }
        __builtin_amdgcn_wave_barrier();
        char* base = (char*)ctp + (size_t)T2*T_STRIDE + V_OFF;
#pragma unroll
        for (int ch=0; ch<8; ++ch) {
          int jcl = ch >> 2, cc = ch & 3;
          int lr0 = jcl*16 + 8*h;
          int c = cc*32 + l;
          uint4 o;
          o.x = (unsigned)xs[(lr0+0)*136 + c] | ((unsigned)xs[(lr0+1)*136 + c] << 16);
          o.y = (unsigned)xs[(lr0+2)*136 + c] | ((unsigned)xs[(lr0+3)*136 + c] << 16);
          o.z = (unsigned)xs[(lr0+4)*136 + c] | ((unsigned)xs[(lr0+5)*136 + c] << 16);
          o.w = (unsigned)xs[(lr0+6)*136 + c] | ((unsigned)xs[(lr0+7)*136 + c] << 16);
          int jc16 = half*2 + jcl;
          *(uint4*)(base + (jc16*4 + cc)*1024 + ln*16) = o;
        }
      }
    }
  }
  gridbar(cnt, (unsigned)nb);

  // ================= Phase 2: main (R5 structure) =================
  {
    unsigned short* stg = (unsigned short*)smraw;            // 34816 B
    unsigned short* gls = (unsigned short*)(smraw + T_STRIDE); // 17408 B
    const int ib = blockIdx.x & 63;
    const int sp = blockIdx.x >> 6;
    const int row = ib*128 + wv*32 + l;

    bf16x8 qf[9];  // Q B-operand: x[row][k], plus k=128,129 -> 1,1 (h=0)
    {
      const float* xr = X + (size_t)row * 128;
#pragma unroll
      for (int kc=0;kc<8;++kc) {
        float4 p0 = *(const float4*)(xr + kc*16 + 8*h);
        float4 p1 = *(const float4*)(xr + kc*16 + 8*h + 4);
        qf[kc] = pack8(p0, p1);
      }
      uint4 o; o.x = (h == 0) ? 0x3F803F80u : 0u; o.y = 0u; o.z = 0u; o.w = 0u;
      qf[8] = __builtin_bit_cast(bf16x8, o);
    }
    f32x16 acc[4];
#pragma unroll
    for (int cc=0;cc<4;++cc)
#pragma unroll
      for (int i=0;i<16;++i) acc[cc][i]=0.f;
    float rs = 0.f;
    const int Tbeg = (sp * 128) / js;
    const int Tend = ((sp + 1) * 128) / js;
    for (int T = Tbeg; T < Tend; ++T) {
      __syncthreads();
      {
        const char* cb = (const char*)ctp + (size_t)T*T_STRIDE;
#pragma unroll
        for (int i=0;i<9;++i) {
          int c = wv + 4*i;
          if (c < 34) gl2lds16(cb + c*1024 + ln*16, (char*)stg + c*1024);
        }
      }
      __syncthreads();
#pragma unroll
      for (int jc=0; jc<2; ++jc) {
        f32x16 sa;
#pragma unroll
        for (int i=0;i<16;++i) sa[i]=0.f;
#pragma unroll
        for (int kc=0;kc<9;++kc) {
          bf16x8 a = *(const bf16x8*)((const char*)stg + (jc*9+kc)*1024 + ln*16);
          sa = mfma_32x32x16(a, qf[kc], sa);
        }
#pragma unroll
        for (int rg=0; rg<4; ++rg) {
          float g0 = fast_exp2(sa[rg*4+0]);
          float g1 = fast_exp2(sa[rg*4+1]);
          float g2 = fast_exp2(sa[rg*4+2]);
          float g3 = fast_exp2(sa[rg*4+3]);
          rs += (g0+g1) + (g2+g3);
          uint2 w; w.x = pk2bf(g0, g1); w.y = pk2bf(g2, g3);
          int j0 = jc*32 + 8*rg + 4*h;
          *(uint2*)&gls[(wv*32+l)*68 + j0] = w;
        }
        __builtin_amdgcn_wave_barrier();
#pragma unroll
        for (int jj=0; jj<2; ++jj) {
          int jc16 = jc*2 + jj;
          const unsigned short* gp = &gls[(wv*32+l)*68 + jc16*16 + 8*h];
          uint2 g0 = *(const uint2*)(gp);
          uint2 g1 = *(const uint2*)(gp + 4);
          uint4 gv; gv.x=g0.x; gv.y=g0.y; gv.z=g1.x; gv.w=g1.y;
          bf16x8 pb = __builtin_bit_cast(bf16x8, gv);
#pragma unroll
          for (int cc=0;cc<4;++cc) {
            bf16x8 a2 = *(const bf16x8*)((const char*)stg + V_OFF + (jc16*4+cc)*1024 + ln*16);
            acc[cc] = mfma_32x32x16(a2, pb, acc[cc]);
          }
        }
        __builtin_amdgcn_wave_barrier();
      }
    }
    rs += __shfl_xor(rs, 32, 64);
    if (h == 0) rsp[(size_t)sp*8192 + row] = rs;
#pragma unroll
    for (int cc=0;cc<4;++cc)
#pragma unroll
      for (int r=0;r<16;++r) {
        int c = cc*32 + (r&3) + 8*(r>>2) + 4*h;
        accp[((size_t)sp*128 + c)*8192 + row] = acc[cc][r];
      }
  }
  gridbar(cnt, (unsigned)(2*nb));

  // ================= Phase 3: fin (512 block-tasks: 32 rows x 64 cols) ==========
  {
    float* trS = (float*)smraw;           // [32][68]
    float* rinvS = trS + 32*68;           // 32 floats
    for (int bt = blockIdx.x; bt < 512; bt += nb) {
      __syncthreads();
      const int r0 = (bt >> 1) * 32;
      const int c0 = (bt & 1) * 64;
      if (tid < 32) {
        float s = 0.f;
        for (int sp=0; sp<js; ++sp) s += rsp[(size_t)sp*8192 + r0 + tid];
        rinvS[tid] = 1.f / s;
      }
      const int rq = tid & 7, cg = tid >> 3;   // rows rq*4..+3, cols c0+cg*2..+1
      float v[2][4];
#pragma unroll
      for (int cc=0;cc<2;++cc)
#pragma unroll
        for (int k=0;k<4;++k) v[cc][k]=0.f;
      for (int sp=0; sp<js; ++sp) {
        const float* base = accp + ((size_t)sp*128 + c0 + cg*2)*8192 + r0 + rq*4;
#pragma unroll
        for (int cc=0; cc<2; ++cc) {
          float4 p = *(const float4*)(base + (size_t)cc*8192);
          v[cc][0]+=p.x; v[cc][1]+=p.y; v[cc][2]+=p.z; v[cc][3]+=p.w;
        }
      }
      __syncthreads();
#pragma unroll
      for (int cc=0;cc<2;++cc)
#pragma unroll
        for (int k=0;k<4;++k)
          trS[(rq*4+k)*68 + cg*2+cc] = v[cc][k] * rinvS[rq*4+k];
      __syncthreads();
      {
        int r = tid >> 3, q = tid & 7;
        int grow = r0 + r;
        if (grow < 8191) {
          float* dst = out + (size_t)grow*128 + c0 + q*8;
          const float* s2 = &trS[r*68 + q*8];
          *(float4*)(dst) = *(const float4*)(s2);
          *(float4*)(dst + 4) = *(const float4*)(s2 + 4);
        }
      }
    }
  }
}

extern "C" void kernel_launch(void* const* d_in, const int* in_sizes, int n_in,
                              void* d_out, int out_size, void* d_ws, size_t ws_size,
                              hipStream_t stream) {
  const float* X = (const float*)d_in[0];
  const float* y = (const float*)d_in[1];
  // d_in[2] = y_next (unused by reference)
  const float* R = (const float*)d_in[3];
  const float* t = (const float*)d_in[4];
  float* out = (float*)d_out;
  char* ws = (char*)d_ws;

  unsigned short* ctp = (unsigned short*)ws;                 // 128 * 34816 = 4.456 MB
  size_t cntoff = (size_t)128 * T_STRIDE;
  unsigned* cnt = (unsigned*)(ws + cntoff);                  // 64 B barrier counters
  size_t rspoff = cntoff + 1024;
  float* rsp  = (float*)(ws + rspoff);                       // js*32 KB
  size_t accoff = rspoff + 512*1024;
  float* accp = (float*)(ws + accoff);                       // js * 4 MB

  int js = 12;  // 64 x 12 = 768 blocks = exactly 3 blocks/CU (co-resident)
  while (js > 1 && accoff + (size_t)js*128*8192*4 > ws_size) js >>= 1;
  int nb = 64 * js;

  hipMemsetAsync(cnt, 0, 64, stream);
  k_fused<<<dim3(nb), dim3(256), 0, stream>>>(y, R, t, X, ctp, cnt, accp, rsp, out, js);
}

// Round 10
// 134.080 us; speedup vs baseline: 5.1284x; 5.1284x over previous
//
#include <hip/hip_runtime.h>
#include <hip/hip_bf16.h>

// Gaussian-kernel regression, fused flash-attention style. 3-kernel structure.
// K_prep: 512 one-wave blocks (grid 512x64): 256x yt=y@R^T+t GEMM -> KA2C*yt
//   perm + yn hi/lo folded into K=144 slot; 256x V=X[1:] transpose perm.
// K_main (round-5 proven, 49.9us): S via 9 MFMAs (exponent folded), exp2,
//   P via per-wave LDS round-trip, PV full-rate; js=12, 3 blocks/CU.
// K_fin : reduce splits (col-split grid), normalize, transpose, store.
// NOTE (R9): grid-wide barriers w/ agent-scope fences on gfx950 = L2
// writeback storms, 12x slowdown. Never again.

#define LOG2E 1.44269504088896340736f
#define KNEG (-(1.0f/256.0f)*LOG2E)
#define KA2C (2.0f*(1.0f/256.0f)*LOG2E)

typedef __attribute__((ext_vector_type(4)))  float f32x4;
typedef __attribute__((ext_vector_type(16))) float f32x16;
typedef __attribute__((ext_vector_type(8)))  short bf16x8;

__device__ __forceinline__ unsigned short f2bf(float f) {
  unsigned u = __builtin_bit_cast(unsigned, f);
  u = (u + 0x7fffu + ((u >> 16) & 1u)) >> 16;  // RNE; inputs finite
  return (unsigned short)u;
}
__device__ __forceinline__ unsigned pk2bf(float a, float b) {
  __hip_bfloat162 h = __float22bfloat162_rn(float2{a, b});  // v_cvt_pk_bf16_f32
  unsigned u;
  __builtin_memcpy(&u, &h, 4);
  return u;
}
__device__ __forceinline__ bf16x8 pack8(float4 p0, float4 p1) {
  uint4 u;
  u.x = pk2bf(p0.x, p0.y); u.y = pk2bf(p0.z, p0.w);
  u.z = pk2bf(p1.x, p1.y); u.w = pk2bf(p1.z, p1.w);
  return __builtin_bit_cast(bf16x8, u);
}
__device__ __forceinline__ float fast_exp2(float x) {
#if __has_builtin(__builtin_amdgcn_exp2f)
  return __builtin_amdgcn_exp2f(x);
#else
  return exp2f(x);
#endif
}
__device__ __forceinline__ void gl2lds16(const void* g, void* l) {
  __builtin_amdgcn_global_load_lds((const __attribute__((address_space(1))) unsigned int*)g,
                                   (__attribute__((address_space(3))) unsigned int*)l, 16, 0, 0);
}
__device__ __forceinline__ f32x16 mfma_32x32x16(bf16x8 a, bf16x8 b, f32x16 c) {
  return __builtin_amdgcn_mfma_f32_32x32x16_bf16(a, b, c, 0, 0, 0);
}

#define T_STRIDE 34816   // per-64j-tile bytes: 2 jc x 9 kc x 1024 (yt) + 16384 (V)
#define V_OFF    18432

// ---------------- K_prep: 512 one-wave blocks ----------------
// task = blockIdx.x. task<256: yt GEMM for 32 rows (tile task>>1, half task&1).
// task>=256: V transpose for 32 X1-rows.
__global__ __launch_bounds__(64) void k_prep(const float* __restrict__ y,
                                             const float* __restrict__ R,
                                             const float* __restrict__ t,
                                             const float* __restrict__ X,
                                             unsigned short* __restrict__ ctp) {
  __shared__ char slice[8704];
  const int task = blockIdx.x;
  const int ln = threadIdx.x;
  const int l = ln & 31, h = ln >> 5;

  if (task < 256) {
    // ---- yt task: rows rw..rw+31; tile T=task>>1, jc half jcw=task&1 ----
    unsigned short* ytt = (unsigned short*)slice;        // [32][132] = 8448 B
    float* ynf = (float*)(slice + 8448);                 // 32 floats
    const int T = task >> 1, jcw = task & 1;
    const int rw = task * 32;
    bf16x8 af[8];
    {
      int row = rw + l; if (row > 8190) row = 8190;
      const float* yr = y + (size_t)row * 128;
#pragma unroll
      for (int kc = 0; kc < 8; ++kc) {
        float4 p0 = *(const float4*)(yr + kc*16 + 8*h);
        float4 p1 = *(const float4*)(yr + kc*16 + 8*h + 4);
        af[kc] = pack8(p0, p1);
      }
    }
    f32x16 ac[4];
#pragma unroll
    for (int cc=0; cc<4; ++cc)
#pragma unroll
      for (int i=0;i<16;++i) ac[cc][i] = 0.f;
#pragma unroll
    for (int cc=0; cc<4; ++cc) {
      const float* Rr = R + (size_t)(cc*32 + l) * 128;   // R^T[k][c] = R[c][k]
#pragma unroll
      for (int kc=0; kc<8; ++kc) {
        float4 p0 = *(const float4*)(Rr + kc*16 + 8*h);
        float4 p1 = *(const float4*)(Rr + kc*16 + 8*h + 4);
        ac[cc] = mfma_32x32x16(af[kc], pack8(p0, p1), ac[cc]);
      }
    }
    // D: lane holds yt[rw + (r&3)+8*(r>>2)+4h][cc*32 + l]
    float tv0 = t[l], tv1 = t[32+l], tv2 = t[64+l], tv3 = t[96+l];
    float v0[16], v1[16], v2[16], v3[16], ssq[16];
#pragma unroll
    for (int r=0;r<16;++r) {
      v0[r]=ac[0][r]+tv0; v1[r]=ac[1][r]+tv1; v2[r]=ac[2][r]+tv2; v3[r]=ac[3][r]+tv3;
      ssq[r] = v0[r]*v0[r] + v1[r]*v1[r] + v2[r]*v2[r] + v3[r]*v3[r];
    }
#pragma unroll
    for (int off=1; off<32; off<<=1)
#pragma unroll
      for (int r=0;r<16;++r) ssq[r] += __shfl_xor(ssq[r], off, 64);
    if (l < 16) {
      int r = l;
      int grow = rw + (r&3) + 8*(r>>2) + 4*h;
      ynf[(r&3) + 8*(r>>2) + 4*h] = (grow >= 8191) ? -1.0e4f : KNEG * ssq[r];
    }
#pragma unroll
    for (int r=0;r<16;++r) {
      int rloc = (r&3) + 8*(r>>2) + 4*h;
      ytt[rloc*132 +   0 + l] = f2bf(KA2C * v0[r]);
      ytt[rloc*132 +  32 + l] = f2bf(KA2C * v1[r]);
      ytt[rloc*132 +  64 + l] = f2bf(KA2C * v2[r]);
      ytt[rloc*132 +  96 + l] = f2bf(KA2C * v3[r]);
    }
    __syncthreads();
    char* base = (char*)ctp + (size_t)T*T_STRIDE;
#pragma unroll
    for (int kc=0;kc<8;++kc) {
      const unsigned short* s = &ytt[l*132 + kc*16 + 8*h];
      uint2 a = *(const uint2*)(s);
      uint2 b = *(const uint2*)(s + 4);
      uint4 o; o.x=a.x; o.y=a.y; o.z=b.x; o.w=b.y;
      *(uint4*)(base + (jcw*9 + kc)*1024 + ln*16) = o;
    }
    {  // kc=8 slot: k=128 -> yn_hi, k=129 -> yn_lo (h=0 lanes only)
      float yn = ynf[l];
      unsigned short hi = f2bf(yn);
      float hif = __builtin_bit_cast(float, (unsigned)hi << 16);
      unsigned short lo = f2bf(yn - hif);
      uint4 o; o.x = (h == 0) ? ((unsigned)hi | ((unsigned)lo << 16)) : 0u;
      o.y = 0u; o.z = 0u; o.w = 0u;
      *(uint4*)(base + (jcw*9 + 8)*1024 + ln*16) = o;
    }
  } else {
    // ---- V task: 32 X1-rows; tile T2=(task-256)>>1, half=(task-256)&1 ----
    unsigned short* xs = (unsigned short*)slice;         // [32][136] bf16 = 8704 B
    const int tv_ = task - 256;
    const int T2 = tv_ >> 1, half = tv_ & 1;
    const int xr0 = T2*64 + half*32 + 1;
    {
      int rl = ln >> 1, ch2 = ln & 1;
      int row = xr0 + rl; if (row > 8191) row = 8191;   // pad j has g=0
      const float* src = X + (size_t)row*128 + ch2*64;
      unsigned short* dst = xs + rl*136 + ch2*64;
#pragma unroll
      for (int i=0;i<8;++i) {
        float4 p0 = *(const float4*)(src + i*8);
        float4 p1 = *(const float4*)(src + i*8 + 4);
        uint4 w;
        w.x = pk2bf(p0.x, p0.y); w.y = pk2bf(p0.z, p0.w);
        w.z = pk2bf(p1.x, p1.y); w.w = pk2bf(p1.z, p1.w);
        *(uint4*)(dst + i*8) = w;
      }
    }
    __syncthreads();
    char* base = (char*)ctp + (size_t)T2*T_STRIDE + V_OFF;
#pragma unroll
    for (int ch=0; ch<8; ++ch) {
      int jcl = ch >> 2, cc = ch & 3;
      int lr0 = jcl*16 + 8*h;
      int c = cc*32 + l;
      uint4 o;
      o.x = (unsigned)xs[(lr0+0)*136 + c] | ((unsigned)xs[(lr0+1)*136 + c] << 16);
      o.y = (unsigned)xs[(lr0+2)*136 + c] | ((unsigned)xs[(lr0+3)*136 + c] << 16);
      o.z = (unsigned)xs[(lr0+4)*136 + c] | ((unsigned)xs[(lr0+5)*136 + c] << 16);
      o.w = (unsigned)xs[(lr0+6)*136 + c] | ((unsigned)xs[(lr0+7)*136 + c] << 16);
      int jc16 = half*2 + jcl;
      *(uint4*)(base + (jc16*4 + cc)*1024 + ln*16) = o;
    }
  }
}

// ---------------- K_main (round-5 proven) ----------------
// grid (64, js); block 256 = 4 waves x 32 query rows (BM=128); 3 blocks/CU.
__global__ __launch_bounds__(256, 3) void k_main(
    const float* __restrict__ X,
    const unsigned short* __restrict__ ctp,
    float* __restrict__ accp,
    float* __restrict__ rsp,
    int js) {
  __shared__ unsigned short stg[T_STRIDE/2];   // 34816 B: yt(9kc x 2jc) + V
  __shared__ unsigned short gls[4*32*68];      // per-wave P scratch, stride 68
  const int tid = threadIdx.x;
  const int wv = tid >> 6, ln = tid & 63;
  const int l = ln & 31, h = ln >> 5;
  const int row = blockIdx.x*128 + wv*32 + l;  // query row, always < 8192

  bf16x8 qf[9];  // Q as B-operand: x[row][k], plus k=128,129 -> 1,1 (h=0)
  {
    const float* xr = X + (size_t)row * 128;
#pragma unroll
    for (int kc=0;kc<8;++kc) {
      float4 p0 = *(const float4*)(xr + kc*16 + 8*h);
      float4 p1 = *(const float4*)(xr + kc*16 + 8*h + 4);
      qf[kc] = pack8(p0, p1);
    }
    uint4 o; o.x = (h == 0) ? 0x3F803F80u : 0u; o.y = 0u; o.z = 0u; o.w = 0u;
    qf[8] = __builtin_bit_cast(bf16x8, o);
  }
  f32x16 acc[4];
#pragma unroll
  for (int cc=0;cc<4;++cc)
#pragma unroll
    for (int i=0;i<16;++i) acc[cc][i]=0.f;
  float rs = 0.f;
  const int sp = blockIdx.y;
  const int Tbeg = (sp * 128) / js;
  const int Tend = ((sp + 1) * 128) / js;
  for (int T = Tbeg; T < Tend; ++T) {
    __syncthreads();  // previous-tile reads done before restage
    {
      const char* cb = (const char*)ctp + (size_t)T*T_STRIDE;
#pragma unroll
      for (int i=0;i<9;++i) {
        int c = wv + 4*i;
        if (c < 34) gl2lds16(cb + c*1024 + ln*16, (char*)stg + c*1024);
      }
    }
    __syncthreads();  // drains vmcnt -> staged data visible
#pragma unroll
    for (int jc=0; jc<2; ++jc) {
      f32x16 sa;
#pragma unroll
      for (int i=0;i<16;++i) sa[i]=0.f;
#pragma unroll
      for (int kc=0;kc<9;++kc) {  // e^T = (KA2C yt)·x + yn  directly
        bf16x8 a = *(const bf16x8*)((const char*)stg + (jc*9+kc)*1024 + ln*16);
        sa = mfma_32x32x16(a, qf[kc], sa);
      }
      // lane holds e[j = jc*32 + i + 8*rg + 4h][m = l] at sa[rg*4+i]
#pragma unroll
      for (int rg=0; rg<4; ++rg) {
        float g0 = fast_exp2(sa[rg*4+0]);
        float g1 = fast_exp2(sa[rg*4+1]);
        float g2 = fast_exp2(sa[rg*4+2]);
        float g3 = fast_exp2(sa[rg*4+3]);
        rs += (g0+g1) + (g2+g3);
        uint2 w; w.x = pk2bf(g0, g1); w.y = pk2bf(g2, g3);
        int j0 = jc*32 + 8*rg + 4*h;
        *(uint2*)&gls[(wv*32+l)*68 + j0] = w;   // 8B-aligned b64 write
      }
      __builtin_amdgcn_wave_barrier();
#pragma unroll
      for (int jj=0; jj<2; ++jj) {
        int jc16 = jc*2 + jj;
        const unsigned short* gp = &gls[(wv*32+l)*68 + jc16*16 + 8*h];
        uint2 g0 = *(const uint2*)(gp);
        uint2 g1 = *(const uint2*)(gp + 4);
        uint4 gv; gv.x=g0.x; gv.y=g0.y; gv.z=g1.x; gv.w=g1.y;
        bf16x8 pb = __builtin_bit_cast(bf16x8, gv);
#pragma unroll
        for (int cc=0;cc<4;++cc) {
          bf16x8 a2 = *(const bf16x8*)((const char*)stg + V_OFF + (jc16*4+cc)*1024 + ln*16);
          acc[cc] = mfma_32x32x16(a2, pb, acc[cc]);
        }
      }
      __builtin_amdgcn_wave_barrier();
    }
  }
  rs += __shfl_xor(rs, 32, 64);
  if (h == 0) rsp[(size_t)sp*8192 + row] = rs;
  // acc^T: lane holds out^T[c = cc*32+(r&3)+8(r>>2)+4h][m = row]; store [sp][c][row]
#pragma unroll
  for (int cc=0;cc<4;++cc)
#pragma unroll
    for (int r=0;r<16;++r) {
      int c = cc*32 + (r&3) + 8*(r>>2) + 4*h;
      accp[((size_t)sp*128 + c)*8192 + row] = acc[cc][r];
    }
}

// ---------------- K_fin: col-split coalesced reduce + normalize + transpose ----------------
// grid (128, 2); block 256. Block: 64 rows x 64 cols.
__global__ __launch_bounds__(256) void k_fin(const float* __restrict__ accp,
                                             const float* __restrict__ rsp,
                                             float* __restrict__ out,
                                             int js) {
  __shared__ float tr[64*68];
  __shared__ float rinv[64];
  const int tid = threadIdx.x;
  const int r0 = blockIdx.x * 64;
  const int c0 = blockIdx.y * 64;
  if (tid < 64) {
    float s = 0.f;
    for (int sp=0; sp<js; ++sp) s += rsp[(size_t)sp*8192 + r0 + tid];
    rinv[tid] = 1.f / s;
  }
  const int rq = tid & 15, cg = tid >> 4;   // rows rq*4..+3, cols c0+cg*4..+3
  float v[4][4];
#pragma unroll
  for (int cc=0;cc<4;++cc)
#pragma unroll
    for (int k=0;k<4;++k) v[cc][k]=0.f;
  for (int sp=0; sp<js; ++sp) {
    const float* base = accp + ((size_t)sp*128 + c0 + cg*4)*8192 + r0 + rq*4;
#pragma unroll
    for (int cc=0; cc<4; ++cc) {
      float4 p = *(const float4*)(base + (size_t)cc*8192);
      v[cc][0]+=p.x; v[cc][1]+=p.y; v[cc][2]+=p.z; v[cc][3]+=p.w;
    }
  }
  __syncthreads();
#pragma unroll
  for (int cc=0;cc<4;++cc)
#pragma unroll
    for (int k=0;k<4;++k)
      tr[(rq*4+k)*68 + cg*4+cc] = v[cc][k] * rinv[rq*4+k];
  __syncthreads();
  {
    int r = tid >> 2, q = tid & 3;
    int grow = r0 + r;
    if (grow < 8191) {
      float* dst = out + (size_t)grow*128 + c0 + q*16;
      const float* s2 = &tr[r*68 + q*16];
#pragma unroll
      for (int i=0;i<4;++i) *(float4*)(dst + i*4) = *(const float4*)(s2 + i*4);
    }
  }
}

extern "C" void kernel_launch(void* const* d_in, const int* in_sizes, int n_in,
                              void* d_out, int out_size, void* d_ws, size_t ws_size,
                              hipStream_t stream) {
  const float* X = (const float*)d_in[0];
  const float* y = (const float*)d_in[1];
  // d_in[2] = y_next (unused by reference)
  const float* R = (const float*)d_in[3];
  const float* t = (const float*)d_in[4];
  float* out = (float*)d_out;
  char* ws = (char*)d_ws;

  unsigned short* ctp = (unsigned short*)ws;                 // 128 * 34816 = 4.456 MB
  size_t rspoff = (size_t)128 * T_STRIDE;
  float* rsp  = (float*)(ws + rspoff);                       // js*32 KB
  size_t accoff = rspoff + 512*1024;
  float* accp = (float*)(ws + accoff);                       // js * 4 MB

  int js = 12;  // 64 x 12 = 768 blocks = exactly 3 blocks/CU
  while (js > 1 && accoff + (size_t)js*128*8192*4 > ws_size) js >>= 1;

  k_prep<<<dim3(512), dim3(64), 0, stream>>>(y, R, t, X, ctp);
  k_main<<<dim3(64, js), dim3(256), 0, stream>>>(X, ctp, accp, rsp, js);
  k_fin<<<dim3(128, 2), dim3(256), 0, stream>>>(accp, rsp, out, js);
}

// Round 11
// 132.300 us; speedup vs baseline: 5.1974x; 1.0135x over previous
//
#include <hip/hip_runtime.h>
#include <hip/hip_bf16.h>

// Gaussian-kernel regression, fused flash-attention style. 3-kernel structure.
// K_prep: 512 one-wave blocks: 256x yt=y@R^T+t GEMM -> KA2C*yt perm + yn hi/lo
//   folded into K=144 slot; 256x V=X[1:] transpose perm.
// K_main (round-5 proven, ~49us): S via 9 MFMAs (exponent folded), exp2,
//   P via per-wave LDS round-trip, PV full-rate; js=12, 3 blocks/CU.
// K_fin : grid (128,4)=512 blocks, sp-loop unrolled x4 -> pipelined 48MB read.
// NOTE (R9): grid-wide barriers w/ agent-scope fences on gfx950 = L2
// writeback storms, 12x slowdown. Never again.

#define LOG2E 1.44269504088896340736f
#define KNEG (-(1.0f/256.0f)*LOG2E)
#define KA2C (2.0f*(1.0f/256.0f)*LOG2E)

typedef __attribute__((ext_vector_type(4)))  float f32x4;
typedef __attribute__((ext_vector_type(16))) float f32x16;
typedef __attribute__((ext_vector_type(8)))  short bf16x8;

__device__ __forceinline__ unsigned short f2bf(float f) {
  unsigned u = __builtin_bit_cast(unsigned, f);
  u = (u + 0x7fffu + ((u >> 16) & 1u)) >> 16;  // RNE; inputs finite
  return (unsigned short)u;
}
__device__ __forceinline__ unsigned pk2bf(float a, float b) {
  __hip_bfloat162 h = __float22bfloat162_rn(float2{a, b});  // v_cvt_pk_bf16_f32
  unsigned u;
  __builtin_memcpy(&u, &h, 4);
  return u;
}
__device__ __forceinline__ bf16x8 pack8(float4 p0, float4 p1) {
  uint4 u;
  u.x = pk2bf(p0.x, p0.y); u.y = pk2bf(p0.z, p0.w);
  u.z = pk2bf(p1.x, p1.y); u.w = pk2bf(p1.z, p1.w);
  return __builtin_bit_cast(bf16x8, u);
}
__device__ __forceinline__ float fast_exp2(float x) {
#if __has_builtin(__builtin_amdgcn_exp2f)
  return __builtin_amdgcn_exp2f(x);
#else
  return exp2f(x);
#endif
}
__device__ __forceinline__ void gl2lds16(const void* g, void* l) {
  __builtin_amdgcn_global_load_lds((const __attribute__((address_space(1))) unsigned int*)g,
                                   (__attribute__((address_space(3))) unsigned int*)l, 16, 0, 0);
}
__device__ __forceinline__ f32x16 mfma_32x32x16(bf16x8 a, bf16x8 b, f32x16 c) {
  return __builtin_amdgcn_mfma_f32_32x32x16_bf16(a, b, c, 0, 0, 0);
}

#define T_STRIDE 34816   // per-64j-tile bytes: 2 jc x 9 kc x 1024 (yt) + 16384 (V)
#define V_OFF    18432

// ---------------- K_prep: 512 one-wave blocks ----------------
// task = blockIdx.x. task<256: yt GEMM for 32 rows (tile task>>1, half task&1).
// task>=256: V transpose for 32 X1-rows.
__global__ __launch_bounds__(64) void k_prep(const float* __restrict__ y,
                                             const float* __restrict__ R,
                                             const float* __restrict__ t,
                                             const float* __restrict__ X,
                                             unsigned short* __restrict__ ctp) {
  __shared__ char slice[8704];
  const int task = blockIdx.x;
  const int ln = threadIdx.x;
  const int l = ln & 31, h = ln >> 5;

  if (task < 256) {
    // ---- yt task: rows rw..rw+31; tile T=task>>1, jc half jcw=task&1 ----
    unsigned short* ytt = (unsigned short*)slice;        // [32][132] = 8448 B
    float* ynf = (float*)(slice + 8448);                 // 32 floats
    const int T = task >> 1, jcw = task & 1;
    const int rw = task * 32;
    bf16x8 af[8];
    {
      int row = rw + l; if (row > 8190) row = 8190;
      const float* yr = y + (size_t)row * 128;
#pragma unroll
      for (int kc = 0; kc < 8; ++kc) {
        float4 p0 = *(const float4*)(yr + kc*16 + 8*h);
        float4 p1 = *(const float4*)(yr + kc*16 + 8*h + 4);
        af[kc] = pack8(p0, p1);
      }
    }
    f32x16 ac[4];
#pragma unroll
    for (int cc=0; cc<4; ++cc)
#pragma unroll
      for (int i=0;i<16;++i) ac[cc][i] = 0.f;
#pragma unroll
    for (int cc=0; cc<4; ++cc) {
      const float* Rr = R + (size_t)(cc*32 + l) * 128;   // R^T[k][c] = R[c][k]
#pragma unroll
      for (int kc=0; kc<8; ++kc) {
        float4 p0 = *(const float4*)(Rr + kc*16 + 8*h);
        float4 p1 = *(const float4*)(Rr + kc*16 + 8*h + 4);
        ac[cc] = mfma_32x32x16(af[kc], pack8(p0, p1), ac[cc]);
      }
    }
    // D: lane holds yt[rw + (r&3)+8*(r>>2)+4h][cc*32 + l]
    float tv0 = t[l], tv1 = t[32+l], tv2 = t[64+l], tv3 = t[96+l];
    float v0[16], v1[16], v2[16], v3[16], ssq[16];
#pragma unroll
    for (int r=0;r<16;++r) {
      v0[r]=ac[0][r]+tv0; v1[r]=ac[1][r]+tv1; v2[r]=ac[2][r]+tv2; v3[r]=ac[3][r]+tv3;
      ssq[r] = v0[r]*v0[r] + v1[r]*v1[r] + v2[r]*v2[r] + v3[r]*v3[r];
    }
#pragma unroll
    for (int off=1; off<32; off<<=1)
#pragma unroll
      for (int r=0;r<16;++r) ssq[r] += __shfl_xor(ssq[r], off, 64);
    if (l < 16) {
      int r = l;
      int grow = rw + (r&3) + 8*(r>>2) + 4*h;
      ynf[(r&3) + 8*(r>>2) + 4*h] = (grow >= 8191) ? -1.0e4f : KNEG * ssq[r];
    }
#pragma unroll
    for (int r=0;r<16;++r) {
      int rloc = (r&3) + 8*(r>>2) + 4*h;
      ytt[rloc*132 +   0 + l] = f2bf(KA2C * v0[r]);
      ytt[rloc*132 +  32 + l] = f2bf(KA2C * v1[r]);
      ytt[rloc*132 +  64 + l] = f2bf(KA2C * v2[r]);
      ytt[rloc*132 +  96 + l] = f2bf(KA2C * v3[r]);
    }
    __syncthreads();
    char* base = (char*)ctp + (size_t)T*T_STRIDE;
#pragma unroll
    for (int kc=0;kc<8;++kc) {
      const unsigned short* s = &ytt[l*132 + kc*16 + 8*h];
      uint2 a = *(const uint2*)(s);
      uint2 b = *(const uint2*)(s + 4);
      uint4 o; o.x=a.x; o.y=a.y; o.z=b.x; o.w=b.y;
      *(uint4*)(base + (jcw*9 + kc)*1024 + ln*16) = o;
    }
    {  // kc=8 slot: k=128 -> yn_hi, k=129 -> yn_lo (h=0 lanes only)
      float yn = ynf[l];
      unsigned short hi = f2bf(yn);
      float hif = __builtin_bit_cast(float, (unsigned)hi << 16);
      unsigned short lo = f2bf(yn - hif);
      uint4 o; o.x = (h == 0) ? ((unsigned)hi | ((unsigned)lo << 16)) : 0u;
      o.y = 0u; o.z = 0u; o.w = 0u;
      *(uint4*)(base + (jcw*9 + 8)*1024 + ln*16) = o;
    }
  } else {
    // ---- V task: 32 X1-rows; tile T2=(task-256)>>1, half=(task-256)&1 ----
    unsigned short* xs = (unsigned short*)slice;         // [32][136] bf16 = 8704 B
    const int tv_ = task - 256;
    const int T2 = tv_ >> 1, half = tv_ & 1;
    const int xr0 = T2*64 + half*32 + 1;
    {
      int rl = ln >> 1, ch2 = ln & 1;
      int row = xr0 + rl; if (row > 8191) row = 8191;   // pad j has g=0
      const float* src = X + (size_t)row*128 + ch2*64;
      unsigned short* dst = xs + rl*136 + ch2*64;
#pragma unroll
      for (int i=0;i<8;++i) {
        float4 p0 = *(const float4*)(src + i*8);
        float4 p1 = *(const float4*)(src + i*8 + 4);
        uint4 w;
        w.x = pk2bf(p0.x, p0.y); w.y = pk2bf(p0.z, p0.w);
        w.z = pk2bf(p1.x, p1.y); w.w = pk2bf(p1.z, p1.w);
        *(uint4*)(dst + i*8) = w;
      }
    }
    __syncthreads();
    char* base = (char*)ctp + (size_t)T2*T_STRIDE + V_OFF;
#pragma unroll
    for (int ch=0; ch<8; ++ch) {
      int jcl = ch >> 2, cc = ch & 3;
      int lr0 = jcl*16 + 8*h;
      int c = cc*32 + l;
      uint4 o;
      o.x = (unsigned)xs[(lr0+0)*136 + c] | ((unsigned)xs[(lr0+1)*136 + c] << 16);
      o.y = (unsigned)xs[(lr0+2)*136 + c] | ((unsigned)xs[(lr0+3)*136 + c] << 16);
      o.z = (unsigned)xs[(lr0+4)*136 + c] | ((unsigned)xs[(lr0+5)*136 + c] << 16);
      o.w = (unsigned)xs[(lr0+6)*136 + c] | ((unsigned)xs[(lr0+7)*136 + c] << 16);
      int jc16 = half*2 + jcl;
      *(uint4*)(base + (jc16*4 + cc)*1024 + ln*16) = o;
    }
  }
}

// ---------------- K_main (round-5 proven) ----------------
// grid (64, js); block 256 = 4 waves x 32 query rows (BM=128); 3 blocks/CU.
__global__ __launch_bounds__(256, 3) void k_main(
    const float* __restrict__ X,
    const unsigned short* __restrict__ ctp,
    float* __restrict__ accp,
    float* __restrict__ rsp,
    int js) {
  __shared__ unsigned short stg[T_STRIDE/2];   // 34816 B: yt(9kc x 2jc) + V
  __shared__ unsigned short gls[4*32*68];      // per-wave P scratch, stride 68
  const int tid = threadIdx.x;
  const int wv = tid >> 6, ln = tid & 63;
  const int l = ln & 31, h = ln >> 5;
  const int row = blockIdx.x*128 + wv*32 + l;  // query row, always < 8192

  bf16x8 qf[9];  // Q as B-operand: x[row][k], plus k=128,129 -> 1,1 (h=0)
  {
    const float* xr = X + (size_t)row * 128;
#pragma unroll
    for (int kc=0;kc<8;++kc) {
      float4 p0 = *(const float4*)(xr + kc*16 + 8*h);
      float4 p1 = *(const float4*)(xr + kc*16 + 8*h + 4);
      qf[kc] = pack8(p0, p1);
    }
    uint4 o; o.x = (h == 0) ? 0x3F803F80u : 0u; o.y = 0u; o.z = 0u; o.w = 0u;
    qf[8] = __builtin_bit_cast(bf16x8, o);
  }
  f32x16 acc[4];
#pragma unroll
  for (int cc=0;cc<4;++cc)
#pragma unroll
    for (int i=0;i<16;++i) acc[cc][i]=0.f;
  float rs = 0.f;
  const int sp = blockIdx.y;
  const int Tbeg = (sp * 128) / js;
  const int Tend = ((sp + 1) * 128) / js;
  for (int T = Tbeg; T < Tend; ++T) {
    __syncthreads();  // previous-tile reads done before restage
    {
      const char* cb = (const char*)ctp + (size_t)T*T_STRIDE;
#pragma unroll
      for (int i=0;i<9;++i) {
        int c = wv + 4*i;
        if (c < 34) gl2lds16(cb + c*1024 + ln*16, (char*)stg + c*1024);
      }
    }
    __syncthreads();  // drains vmcnt -> staged data visible
#pragma unroll
    for (int jc=0; jc<2; ++jc) {
      f32x16 sa;
#pragma unroll
      for (int i=0;i<16;++i) sa[i]=0.f;
#pragma unroll
      for (int kc=0;kc<9;++kc) {  // e^T = (KA2C yt)·x + yn  directly
        bf16x8 a = *(const bf16x8*)((const char*)stg + (jc*9+kc)*1024 + ln*16);
        sa = mfma_32x32x16(a, qf[kc], sa);
      }
      // lane holds e[j = jc*32 + i + 8*rg + 4h][m = l] at sa[rg*4+i]
#pragma unroll
      for (int rg=0; rg<4; ++rg) {
        float g0 = fast_exp2(sa[rg*4+0]);
        float g1 = fast_exp2(sa[rg*4+1]);
        float g2 = fast_exp2(sa[rg*4+2]);
        float g3 = fast_exp2(sa[rg*4+3]);
        rs += (g0+g1) + (g2+g3);
        uint2 w; w.x = pk2bf(g0, g1); w.y = pk2bf(g2, g3);
        int j0 = jc*32 + 8*rg + 4*h;
        *(uint2*)&gls[(wv*32+l)*68 + j0] = w;   // 8B-aligned b64 write
      }
      __builtin_amdgcn_wave_barrier();
#pragma unroll
      for (int jj=0; jj<2; ++jj) {
        int jc16 = jc*2 + jj;
        const unsigned short* gp = &gls[(wv*32+l)*68 + jc16*16 + 8*h];
        uint2 g0 = *(const uint2*)(gp);
        uint2 g1 = *(const uint2*)(gp + 4);
        uint4 gv; gv.x=g0.x; gv.y=g0.y; gv.z=g1.x; gv.w=g1.y;
        bf16x8 pb = __builtin_bit_cast(bf16x8, gv);
#pragma unroll
        for (int cc=0;cc<4;++cc) {
          bf16x8 a2 = *(const bf16x8*)((const char*)stg + V_OFF + (jc16*4+cc)*1024 + ln*16);
          acc[cc] = mfma_32x32x16(a2, pb, acc[cc]);
        }
      }
      __builtin_amdgcn_wave_barrier();
    }
  }
  rs += __shfl_xor(rs, 32, 64);
  if (h == 0) rsp[(size_t)sp*8192 + row] = rs;
  // acc^T: lane holds out^T[c = cc*32+(r&3)+8(r>>2)+4h][m = row]; store [sp][c][row]
#pragma unroll
  for (int cc=0;cc<4;++cc)
#pragma unroll
    for (int r=0;r<16;++r) {
      int c = cc*32 + (r&3) + 8*(r>>2) + 4*h;
      accp[((size_t)sp*128 + c)*8192 + row] = acc[cc][r];
    }
}

// ---------------- K_fin: pipelined split-reduce + normalize + transpose --------
// grid (128, 4) = 512 blocks (2/CU). Block: 64 rows x 32 cols.
// Thread: rows rq*4..+3 (r-contig float4), cols c0 + cg*2..+1. sp-loop unroll 4
// -> 8 float4 loads in flight per thread.
__global__ __launch_bounds__(256) void k_fin(const float* __restrict__ accp,
                                             const float* __restrict__ rsp,
                                             float* __restrict__ out,
                                             int js) {
  __shared__ float tr[64*36];   // stride 36 floats (144 B, 16B-aligned rows)
  __shared__ float rinv[64];
  const int tid = threadIdx.x;
  const int r0 = blockIdx.x * 64;
  const int c0 = blockIdx.y * 32;
  if (tid < 64) {
    float s = 0.f;
    for (int sp=0; sp<js; ++sp) s += rsp[(size_t)sp*8192 + r0 + tid];
    rinv[tid] = 1.f / s;
  }
  const int rq = tid & 15, cg = tid >> 4;   // rows rq*4..+3, cols c0+cg*2..+1
  float v[2][4];
#pragma unroll
  for (int cc=0;cc<2;++cc)
#pragma unroll
    for (int k=0;k<4;++k) v[cc][k]=0.f;
#pragma unroll 4
  for (int sp=0; sp<js; ++sp) {
    const float* base = accp + ((size_t)sp*128 + c0 + cg*2)*8192 + r0 + rq*4;
    float4 p0 = *(const float4*)(base);
    float4 p1 = *(const float4*)(base + 8192);
    v[0][0]+=p0.x; v[0][1]+=p0.y; v[0][2]+=p0.z; v[0][3]+=p0.w;
    v[1][0]+=p1.x; v[1][1]+=p1.y; v[1][2]+=p1.z; v[1][3]+=p1.w;
  }
  __syncthreads();
#pragma unroll
  for (int cc=0;cc<2;++cc)
#pragma unroll
    for (int k=0;k<4;++k)
      tr[(rq*4+k)*36 + cg*2+cc] = v[cc][k] * rinv[rq*4+k];
  __syncthreads();
  {
    int r = tid >> 2, q = tid & 3;   // 64 rows x 4 col-groups of 8
    int grow = r0 + r;
    if (grow < 8191) {
      float* dst = out + (size_t)grow*128 + c0 + q*8;
      const float* s2 = &tr[r*36 + q*8];
      *(float4*)(dst)     = *(const float4*)(s2);
      *(float4*)(dst + 4) = *(const float4*)(s2 + 4);
    }
  }
}

extern "C" void kernel_launch(void* const* d_in, const int* in_sizes, int n_in,
                              void* d_out, int out_size, void* d_ws, size_t ws_size,
                              hipStream_t stream) {
  const float* X = (const float*)d_in[0];
  const float* y = (const float*)d_in[1];
  // d_in[2] = y_next (unused by reference)
  const float* R = (const float*)d_in[3];
  const float* t = (const float*)d_in[4];
  float* out = (float*)d_out;
  char* ws = (char*)d_ws;

  unsigned short* ctp = (unsigned short*)ws;                 // 128 * 34816 = 4.456 MB
  size_t rspoff = (size_t)128 * T_STRIDE;
  float* rsp  = (float*)(ws + rspoff);                       // js*32 KB
  size_t accoff = rspoff + 512*1024;
  float* accp = (float*)(ws + accoff);                       // js * 4 MB

  int js = 12;  // 64 x 12 = 768 blocks = exactly 3 blocks/CU
  while (js > 1 && accoff + (size_t)js*128*8192*4 > ws_size) js >>= 1;

  k_prep<<<dim3(512), dim3(64), 0, stream>>>(y, R, t, X, ctp);
  k_main<<<dim3(64, js), dim3(256), 0, stream>>>(X, ctp, accp, rsp, js);
  k_fin<<<dim3(128, 4), dim3(256), 0, stream>>>(accp, rsp, out, js);
}